// Round 2
// baseline (2282.789 us; speedup 1.0000x reference)
//
#include <hip/hip_runtime.h>
#include <hip/hip_bf16.h>

#define N_NODES 50000
#define N_EDGES 600000
#define CH 128
#define N_LAYERS 15
#define LAP_BLOCKS 2048

typedef float f32x4 __attribute__((ext_vector_type(4)));
typedef short s16x8 __attribute__((ext_vector_type(8)));
typedef unsigned short u16x4 __attribute__((ext_vector_type(4)));

#define LD8(p) (*(const s16x8*)(p))

__device__ __forceinline__ float eluf(float v) {
    return v > 0.f ? v : (__expf(v) - 1.f);
}

// float -> bf16 round-to-nearest-even, raw ushort
__device__ __forceinline__ unsigned short f2bf(float f) {
    unsigned int u = __float_as_uint(f);
    unsigned int r = (u + 0x7FFFu + ((u >> 16) & 1u)) >> 16;
    return (unsigned short)r;
}
__device__ __forceinline__ float bf2f(unsigned short h) {
    return __uint_as_float(((unsigned int)h) << 16);
}

// ---------------- conv1: [N,3] @ [3,128] + b ; writes x fp32 + elu planes ----------------
__global__ __launch_bounds__(256) void conv1_kernel(
    const float* __restrict__ in, const float* __restrict__ W1,
    const float* __restrict__ b1, float* __restrict__ x,
    unsigned short* __restrict__ hbh, unsigned short* __restrict__ hbl, int n)
{
    int idx = blockIdx.x * blockDim.x + threadIdx.x;
    if (idx >= n * CH) return;
    int node = idx >> 7;
    int c = idx & 127;
    float o = b1[c]
            + in[(size_t)node * 3 + 0] * W1[0 * CH + c]
            + in[(size_t)node * 3 + 1] * W1[1 * CH + c]
            + in[(size_t)node * 3 + 2] * W1[2 * CH + c];
    x[idx] = o;
    float e = eluf(o);
    unsigned short hi = f2bf(e);
    hbh[idx] = hi;
    hbl[idx] = f2bf(e - bf2f(hi));
}

// ---------------- zero helpers ----------------
__global__ __launch_bounds__(256) void zero_int_kernel(int* __restrict__ p, int n) {
    int i = blockIdx.x * blockDim.x + threadIdx.x;
    if (i < n) p[i] = 0;
}
__global__ __launch_bounds__(256) void zero_float_kernel(float* __restrict__ p, int n) {
    int i = blockIdx.x * blockDim.x + threadIdx.x;
    if (i < n) p[i] = 0.f;
}

// ---------------- CSR build ----------------
__global__ __launch_bounds__(256) void count_kernel(
    const int* __restrict__ row, int* __restrict__ cnt, int e)
{
    int i = blockIdx.x * blockDim.x + threadIdx.x;
    if (i < e) atomicAdd(&cnt[row[i]], 1);
}

__global__ __launch_bounds__(1024) void block_reduce_kernel(
    const int* __restrict__ cnt, int* __restrict__ bsum, int n)
{
    __shared__ int sd[1024];
    int tid = threadIdx.x;
    int i = blockIdx.x * 1024 + tid;
    sd[tid] = (i < n) ? cnt[i] : 0;
    __syncthreads();
    for (int off = 512; off > 0; off >>= 1) {
        if (tid < off) sd[tid] += sd[tid + off];
        __syncthreads();
    }
    if (tid == 0) bsum[blockIdx.x] = sd[0];
}

__global__ __launch_bounds__(64) void scan_small_kernel(
    const int* __restrict__ bsum, int* __restrict__ boff, int nb)
{
    int lane = threadIdx.x;
    int orig = (lane < nb) ? bsum[lane] : 0;
    int v = orig;
#pragma unroll
    for (int d = 1; d < 64; d <<= 1) {
        int t = __shfl_up(v, d, 64);
        if (lane >= d) v += t;
    }
    if (lane < nb) boff[lane] = v - orig;  // exclusive
}

__global__ __launch_bounds__(1024) void block_scan_kernel(
    const int* __restrict__ cnt, const int* __restrict__ boff,
    int* __restrict__ row_ptr, int n)
{
    __shared__ int sd[1024];
    int tid = threadIdx.x;
    int i = blockIdx.x * 1024 + tid;
    sd[tid] = (i < n) ? cnt[i] : 0;
    __syncthreads();
    for (int off = 1; off < 1024; off <<= 1) {
        int t = (tid >= off) ? sd[tid - off] : 0;
        __syncthreads();
        sd[tid] += t;
        __syncthreads();
    }
    if (i < n) row_ptr[i + 1] = sd[tid] + boff[blockIdx.x];
    if (i == 0) row_ptr[0] = 0;
}

// col_s stores byte offset of the gather row start: col * CH * 2 = col << 8
__global__ __launch_bounds__(256) void fill_kernel(
    const int* __restrict__ row, const int* __restrict__ col,
    const float* __restrict__ val, int* __restrict__ cursor,
    const int* __restrict__ row_ptr, int* __restrict__ col_s,
    float* __restrict__ val_s, int e)
{
    int i = blockIdx.x * blockDim.x + threadIdx.x;
    if (i >= e) return;
    int r = row[i];
    int pos = atomicAdd(&cursor[r], 1);
    int dst = row_ptr[r] + pos;
    col_s[dst] = col[i] << 8;
    val_s[dst] = val[i];
}

// ---------------- mask denominator (once per call) ----------------
__global__ __launch_bounds__(256) void mask_sum_kernel(
    const float* __restrict__ mask, float* __restrict__ denom, int n)
{
    __shared__ float sd[256];
    int tid = threadIdx.x;
    float s = 0.f;
    for (int i = blockIdx.x * 256 + tid; i < n; i += gridDim.x * 256) s += mask[i];
    sd[tid] = s;
    __syncthreads();
    for (int off = 128; off > 0; off >>= 1) {
        if (tid < off) sd[tid] += sd[tid + off];
        __syncthreads();
    }
    if (tid == 0) atomicAdd(denom, sd[0]);
}

// ---- W pre-split into MFMA-FRAGMENT-ordered layout:
// Wf[s][plane][chunk c][ntile][lane=q*16+c16][8 shorts] — wave B-fragment loads
// are 16B/lane coalesced straight from L2 (no LDS staging).
__global__ __launch_bounds__(256) void split_w_kernel(
    const float* __restrict__ W, unsigned short* __restrict__ Wf, int total)
{
    int id = blockIdx.x * 256 + threadIdx.x;
    if (id >= total) return;
    int s = id >> 15;
    int rem = id & 32767;
    int k = rem >> 7;                 // 0..255
    int nn = rem & 127;               // col
    float a = W[id];
    unsigned short hi = f2bf(a);
    float r = a - bf2f(hi);
    unsigned short mi = f2bf(r);
    int c   = k >> 5;                 // chunk
    int kin = k & 31;
    int q   = kin >> 3;
    int ko  = kin & 7;
    int nt  = nn >> 4;
    int c16 = nn & 15;
    int lane = q * 16 + c16;
    size_t base = (size_t)s * 65536 + (size_t)c * 4096 + (size_t)nt * 512
                + (size_t)lane * 8 + ko;
    Wf[base]         = hi;
    Wf[base + 32768] = mi;
}

// ---------------- Laplacian: prop[row,:] = sum_e val * hb[col,:]
// PERSISTENT: 2048 blocks; each wave-unit grid-strides over rows.
// cols are pre-scaled byte offsets. Writes single hi bf16 plane.
__global__ __launch_bounds__(256) void lap_kernel(
    const int* __restrict__ rp, const int* __restrict__ cols,
    const float* __restrict__ vals, const unsigned short* __restrict__ hb,
    unsigned short* __restrict__ ph, int n)
{
    int unit = (blockIdx.x * 256 + threadIdx.x) >> 6;    // global wave id
    int lane = threadIdx.x & 63;
    int ch2 = ((((unit & 1) << 6) + lane) << 1);         // byte offset in gather row
    int stride = (LAP_BLOCKS * 4) >> 1;                  // row stride (2 units/row)
    const char* hbase = (const char*)hb;
    for (int row = unit >> 1; row < n; row += stride) {
        int s = rp[row], e = rp[row + 1];
        float acc = 0.f;
        int t = s;
        for (; t + 8 <= e; t += 8) {
            int c0 = cols[t],     c1 = cols[t + 1], c2 = cols[t + 2], c3 = cols[t + 3];
            int c4 = cols[t + 4], c5 = cols[t + 5], c6 = cols[t + 6], c7 = cols[t + 7];
            float v0 = vals[t],     v1 = vals[t + 1], v2 = vals[t + 2], v3 = vals[t + 3];
            float v4 = vals[t + 4], v5 = vals[t + 5], v6 = vals[t + 6], v7 = vals[t + 7];
            float h0 = bf2f(*(const unsigned short*)(hbase + c0 + ch2));
            float h1 = bf2f(*(const unsigned short*)(hbase + c1 + ch2));
            float h2 = bf2f(*(const unsigned short*)(hbase + c2 + ch2));
            float h3 = bf2f(*(const unsigned short*)(hbase + c3 + ch2));
            float h4 = bf2f(*(const unsigned short*)(hbase + c4 + ch2));
            float h5 = bf2f(*(const unsigned short*)(hbase + c5 + ch2));
            float h6 = bf2f(*(const unsigned short*)(hbase + c6 + ch2));
            float h7 = bf2f(*(const unsigned short*)(hbase + c7 + ch2));
            acc += v0 * h0 + v1 * h1 + v2 * h2 + v3 * h3
                 + v4 * h4 + v5 * h5 + v6 * h6 + v7 * h7;
        }
        for (; t + 4 <= e; t += 4) {
            int c0 = cols[t], c1 = cols[t + 1], c2 = cols[t + 2], c3 = cols[t + 3];
            float v0 = vals[t], v1 = vals[t + 1], v2 = vals[t + 2], v3 = vals[t + 3];
            float h0 = bf2f(*(const unsigned short*)(hbase + c0 + ch2));
            float h1 = bf2f(*(const unsigned short*)(hbase + c1 + ch2));
            float h2 = bf2f(*(const unsigned short*)(hbase + c2 + ch2));
            float h3 = bf2f(*(const unsigned short*)(hbase + c3 + ch2));
            acc += v0 * h0 + v1 * h1 + v2 * h2 + v3 * h3;
        }
        for (; t < e; ++t)
            acc += vals[t] * bf2f(*(const unsigned short*)(hbase + cols[t] + ch2));
        ph[row * CH + (ch2 >> 1)] = f2bf(acc);
    }
}

// ---------------- MFMA GEMM: 32-row tile, 4 waves (32r x 32c each), reg-direct
// A+B with one-chunk-ahead pipeline, LDS-transposed COALESCED epilogue
// (full-line float4 / ushort4 stores instead of column-strided scatter).
// Grid 1563 blocks -> ~6 blocks/CU available; launch_bounds(256,5) -> 20 waves/CU.
__global__ __launch_bounds__(256, 5) void gemm_mfma_kernel(
    const unsigned short* __restrict__ Ah, const unsigned short* __restrict__ Al,
    const unsigned short* __restrict__ Ph,
    const unsigned short* __restrict__ Wf, const float* __restrict__ bias,
    const float* __restrict__ res, float* __restrict__ out,
    unsigned short* __restrict__ hbh, unsigned short* __restrict__ hbl,
    const float* __restrict__ mask, float* __restrict__ accp,
    const float* __restrict__ accv, const float* __restrict__ denom,
    const float* __restrict__ Wb,
    int n, int nch)
{
    __shared__ float tile[32 * 132];              // padded stride 132 (16.9 KB)
    __shared__ float csum[128];
    __shared__ float avg_s[128];
    __shared__ float partial[256];
    __shared__ float bias_s[128];
    const int tid = threadIdx.x;
    const int m_base = blockIdx.x * 32;
    const int wn = tid >> 6;                      // wave col-quarter 0..3
    const int lane = tid & 63;
    const int q = lane >> 4, c16 = lane & 15;

    // per-lane A fragment addresses (element offsets; chunk advances by +32)
    const int aoff0 = (m_base + c16) * CH + q * 8;        // mt=0
    const int aoff1 = aoff0 + 16 * CH;                    // mt=1
    const unsigned short* wp = Wf + wn * 1024 + lane * 8; // B base (2 ntiles/wave)

    f32x4 acc[2][2];
#pragma unroll
    for (int i = 0; i < 2; i++)
#pragma unroll
        for (int j = 0; j < 2; j++) acc[i][j] = (f32x4){0.f, 0.f, 0.f, 0.f};

    // chunk-0 loads in flight across the bias/avg prologue
    s16x8 aH0 = LD8(Ah + aoff0), aH1 = LD8(Ah + aoff1);
    s16x8 aL0 = LD8(Al + aoff0), aL1 = LD8(Al + aoff1);
    s16x8 bh0 = LD8(wp),          bh1 = LD8(wp + 512);
    s16x8 bl0 = LD8(wp + 32768),  bl1 = LD8(wp + 32768 + 512);

    if (tid < 128) {
        bias_s[tid] = bias[tid];
        if (accv) avg_s[tid] = accv[tid] / denom[0];
    }
    __syncthreads();   // bias_s (+avg_s) visible to all waves
    // in-kernel bias2: bias_s += (acc/denom) @ Wb  (avg steps only; block-uniform)
    if (accv) {
        int c = tid & 127;
        int h = tid >> 7;
        float o = 0.f;
#pragma unroll 8
        for (int k = h * 64; k < h * 64 + 64; ++k) o += avg_s[k] * Wb[(size_t)k * CH + c];
        partial[tid] = o;
        __syncthreads();
        if (tid < 128) bias_s[tid] += partial[tid] + partial[tid + 128];
        // visibility to epilogue via the epilogue-start barrier below
    }

    s16x8 p0, p1;                                  // prop A pipeline regs
    // ---- dense chunks 0..3 (hi+lo A planes, 3 MFMA per tile) ----
#pragma unroll
    for (int ch = 0; ch < 4; ++ch) {
        s16x8 nH0, nH1, nL0, nL1, nbh0, nbh1, nbl0, nbl1;
        if (ch < 3) {
            nH0 = LD8(Ah + aoff0 + (ch + 1) * 32);
            nH1 = LD8(Ah + aoff1 + (ch + 1) * 32);
            nL0 = LD8(Al + aoff0 + (ch + 1) * 32);
            nL1 = LD8(Al + aoff1 + (ch + 1) * 32);
        } else if (nch > 4) {
            p0 = LD8(Ph + aoff0);
            p1 = LD8(Ph + aoff1);
        }
        if (ch < 3 || nch > 4) {
            const unsigned short* nwp = wp + (ch + 1) * 4096;
            nbh0 = LD8(nwp);          nbh1 = LD8(nwp + 512);
            nbl0 = LD8(nwp + 32768);  nbl1 = LD8(nwp + 32768 + 512);
        }
        {
            f32x4 c;
            c = acc[0][0];
            c = __builtin_amdgcn_mfma_f32_16x16x32_bf16(aH0, bh0, c, 0, 0, 0);
            c = __builtin_amdgcn_mfma_f32_16x16x32_bf16(aH0, bl0, c, 0, 0, 0);
            c = __builtin_amdgcn_mfma_f32_16x16x32_bf16(aL0, bh0, c, 0, 0, 0);
            acc[0][0] = c;
            c = acc[0][1];
            c = __builtin_amdgcn_mfma_f32_16x16x32_bf16(aH0, bh1, c, 0, 0, 0);
            c = __builtin_amdgcn_mfma_f32_16x16x32_bf16(aH0, bl1, c, 0, 0, 0);
            c = __builtin_amdgcn_mfma_f32_16x16x32_bf16(aL0, bh1, c, 0, 0, 0);
            acc[0][1] = c;
            c = acc[1][0];
            c = __builtin_amdgcn_mfma_f32_16x16x32_bf16(aH1, bh0, c, 0, 0, 0);
            c = __builtin_amdgcn_mfma_f32_16x16x32_bf16(aH1, bl0, c, 0, 0, 0);
            c = __builtin_amdgcn_mfma_f32_16x16x32_bf16(aL1, bh0, c, 0, 0, 0);
            acc[1][0] = c;
            c = acc[1][1];
            c = __builtin_amdgcn_mfma_f32_16x16x32_bf16(aH1, bh1, c, 0, 0, 0);
            c = __builtin_amdgcn_mfma_f32_16x16x32_bf16(aH1, bl1, c, 0, 0, 0);
            c = __builtin_amdgcn_mfma_f32_16x16x32_bf16(aL1, bh1, c, 0, 0, 0);
            acc[1][1] = c;
        }
        if (ch < 3) { aH0 = nH0; aH1 = nH1; aL0 = nL0; aL1 = nL1; }
        if (ch < 3 || nch > 4) { bh0 = nbh0; bh1 = nbh1; bl0 = nbl0; bl1 = nbl1; }
    }
    // ---- prop chunks 4..7 (hi A plane only, 2 MFMA per tile) ----
    if (nch > 4) {
#pragma unroll
        for (int cc = 0; cc < 4; ++cc) {
            s16x8 np0, np1, nbh0, nbh1, nbl0, nbl1;
            if (cc < 3) {
                np0 = LD8(Ph + aoff0 + (cc + 1) * 32);
                np1 = LD8(Ph + aoff1 + (cc + 1) * 32);
                const unsigned short* nwp = wp + (5 + cc) * 4096;
                nbh0 = LD8(nwp);          nbh1 = LD8(nwp + 512);
                nbl0 = LD8(nwp + 32768);  nbl1 = LD8(nwp + 32768 + 512);
            }
            {
                f32x4 c;
                c = acc[0][0];
                c = __builtin_amdgcn_mfma_f32_16x16x32_bf16(p0, bh0, c, 0, 0, 0);
                c = __builtin_amdgcn_mfma_f32_16x16x32_bf16(p0, bl0, c, 0, 0, 0);
                acc[0][0] = c;
                c = acc[0][1];
                c = __builtin_amdgcn_mfma_f32_16x16x32_bf16(p0, bh1, c, 0, 0, 0);
                c = __builtin_amdgcn_mfma_f32_16x16x32_bf16(p0, bl1, c, 0, 0, 0);
                acc[0][1] = c;
                c = acc[1][0];
                c = __builtin_amdgcn_mfma_f32_16x16x32_bf16(p1, bh0, c, 0, 0, 0);
                c = __builtin_amdgcn_mfma_f32_16x16x32_bf16(p1, bl0, c, 0, 0, 0);
                acc[1][0] = c;
                c = acc[1][1];
                c = __builtin_amdgcn_mfma_f32_16x16x32_bf16(p1, bh1, c, 0, 0, 0);
                c = __builtin_amdgcn_mfma_f32_16x16x32_bf16(p1, bl1, c, 0, 0, 0);
                acc[1][1] = c;
            }
            if (cc < 3) { p0 = np0; p1 = np1; bh0 = nbh0; bh1 = nbh1; bl0 = nbl0; bl1 = nbl1; }
        }
    }

    // ---- epilogue: LDS-transposed coalesced stores ----
    __syncthreads();                        // bias_s final; tile buffer free
    if (accp && tid < 128) csum[tid] = 0.f;

    float oreg[2][2][4];
#pragma unroll
    for (int mt = 0; mt < 2; ++mt)
#pragma unroll
        for (int nt = 0; nt < 2; ++nt) {
            int col = wn * 32 + nt * 16 + c16;
            float bv = bias_s[col];
#pragma unroll
            for (int r = 0; r < 4; ++r) {
                int row = m_base + mt * 16 + q * 4 + r;
                float o = acc[mt][nt][r] + bv;
                if (res) o += res[(size_t)row * CH + col];
                oreg[mt][nt][r] = o;
            }
        }

    if (out) {
#pragma unroll
        for (int mt = 0; mt < 2; ++mt)
#pragma unroll
            for (int nt = 0; nt < 2; ++nt)
#pragma unroll
                for (int r = 0; r < 4; ++r)
                    tile[(mt * 16 + q * 4 + r) * 132 + wn * 32 + nt * 16 + c16] =
                        oreg[mt][nt][r];
        __syncthreads();
        for (int e4 = tid; e4 < 1024; e4 += 256) {
            int row = e4 >> 5, c4 = (e4 & 31) << 2;
            if (m_base + row < n)
                *(f32x4*)(out + (size_t)(m_base + row) * CH + c4) =
                    *(const f32x4*)&tile[row * 132 + c4];
        }
        __syncthreads();
    }

    // hb pass: pack (hi<<16|lo) into LDS, flush as ushort4 per plane
    unsigned int* tu = (unsigned int*)tile;
    float colsum[2] = {0.f, 0.f};
#pragma unroll
    for (int mt = 0; mt < 2; ++mt)
#pragma unroll
        for (int nt = 0; nt < 2; ++nt)
#pragma unroll
            for (int r = 0; r < 4; ++r) {
                int row = m_base + mt * 16 + q * 4 + r;
                float e = eluf(oreg[mt][nt][r]);
                unsigned short hi = f2bf(e);
                unsigned short lo = f2bf(e - bf2f(hi));
                tu[(mt * 16 + q * 4 + r) * 132 + wn * 32 + nt * 16 + c16] =
                    ((unsigned int)hi << 16) | lo;
                if (accp && row < n) colsum[nt] += mask[row] * e;
            }
    __syncthreads();
    for (int e4 = tid; e4 < 1024; e4 += 256) {
        int row = e4 >> 5, c4 = (e4 & 31) << 2;
        if (m_base + row < n) {
            uint4 U = *(const uint4*)&tu[row * 132 + c4];
            u16x4 h = { (unsigned short)(U.x >> 16), (unsigned short)(U.y >> 16),
                        (unsigned short)(U.z >> 16), (unsigned short)(U.w >> 16) };
            u16x4 l = { (unsigned short)(U.x & 0xFFFFu), (unsigned short)(U.y & 0xFFFFu),
                        (unsigned short)(U.z & 0xFFFFu), (unsigned short)(U.w & 0xFFFFu) };
            size_t o8 = (size_t)(m_base + row) * CH + c4;
            *(u16x4*)(hbh + o8) = h;
            *(u16x4*)(hbl + o8) = l;
        }
    }

    if (accp) {
        atomicAdd(&csum[wn * 32 + c16], colsum[0]);
        atomicAdd(&csum[wn * 32 + 16 + c16], colsum[1]);
        __syncthreads();
        if (tid < 128) atomicAdd(&accp[tid], csum[tid]);
    }
}

// ---------------- final head: out[n] = elu(x) @ W2 + b2 + inputs[n,0]; persistent ----------------
__global__ __launch_bounds__(256) void final_kernel(
    const unsigned short* __restrict__ hh, const unsigned short* __restrict__ hl,
    const float* __restrict__ W2, const float* __restrict__ b2,
    const float* __restrict__ in, float* __restrict__ out, int n)
{
    int wave = (blockIdx.x * blockDim.x + threadIdx.x) >> 6;
    int lane = threadIdx.x & 63;
    int stride = gridDim.x * 4;
    for (int row = wave; row < n; row += stride) {
        size_t i1 = (size_t)row * CH + lane;
        size_t i2 = i1 + 64;
        float v = (bf2f(hh[i1]) + bf2f(hl[i1])) * W2[lane]
                + (bf2f(hh[i2]) + bf2f(hl[i2])) * W2[64 + lane];
#pragma unroll
        for (int off = 32; off > 0; off >>= 1) v += __shfl_down(v, off, 64);
        if (lane == 0) out[row] = v + b2[0] + in[(size_t)row * 3];
    }
}

extern "C" void kernel_launch(void* const* d_in, const int* in_sizes, int n_in,
                              void* d_out, int out_size, void* d_ws, size_t ws_size,
                              hipStream_t stream)
{
    const int*   L_row   = (const int*)d_in[0];
    const int*   L_col   = (const int*)d_in[1];
    const float* L_val   = (const float*)d_in[2];
    const float* mask    = (const float*)d_in[3];
    const float* inputs  = (const float*)d_in[4];
    const float* conv1_W = (const float*)d_in[5];
    const float* conv1_b = (const float*)d_in[6];
    const float* blocks_W = (const float*)d_in[7];
    const float* blocks_b = (const float*)d_in[8];
    const float* conv2_W = (const float*)d_in[9];
    const float* conv2_b = (const float*)d_in[10];
    float* out = (float*)d_out;

    const int N = N_NODES, E = N_EDGES;
    const size_t NF = (size_t)N * CH;
    const int NPAD = 50048;
    const int NB = (N + 1023) / 1024;

    float* ws = (float*)d_ws;
    float* x0 = ws;                                   // fp32 residual chain (2 slots)
    float* x1 = x0 + NF;
    unsigned short* hbh0 = (unsigned short*)(x1 + NF);  // elu planes, slot 0
    unsigned short* hbl0 = hbh0 + NF;
    unsigned short* hbh1 = hbl0 + NF;                   // elu planes, slot 1
    unsigned short* hbl1 = hbh1 + NF;
    unsigned short* ph   = hbl1 + NF;                   // prop hi plane
    int* cnt     = (int*)(ph + 2 * NF);                 // (gap keeps prior layout size)
    int* cursor  = cnt + NPAD;
    int* row_ptr = cursor + NPAD;
    int* bsum    = row_ptr + NPAD;
    int* boff    = bsum + 64;
    int* col_s   = boff + 64;
    float* val_s = (float*)(col_s + E);
    float* acc_base = val_s + E;                        // 14 slots x 128
    float* denom    = acc_base + 14 * CH;
    unsigned short* wt = (unsigned short*)(denom + 16 + 160);  // 30*65536 shorts (frag order)

    zero_int_kernel<<<(2 * NPAD + 255) / 256, 256, 0, stream>>>(cnt, 2 * NPAD);
    zero_float_kernel<<<(14 * CH + 16 + 255) / 256, 256, 0, stream>>>(acc_base, 14 * CH + 16);
    count_kernel<<<(E + 255) / 256, 256, 0, stream>>>(L_row, cnt, E);
    block_reduce_kernel<<<NB, 1024, 0, stream>>>(cnt, bsum, N);
    scan_small_kernel<<<1, 64, 0, stream>>>(bsum, boff, NB);
    block_scan_kernel<<<NB, 1024, 0, stream>>>(cnt, boff, row_ptr, N);
    fill_kernel<<<(E + 255) / 256, 256, 0, stream>>>(L_row, L_col, L_val, cursor,
                                                     row_ptr, col_s, val_s, E);
    mask_sum_kernel<<<64, 256, 0, stream>>>(mask, denom, N);
    split_w_kernel<<<(30 * 32768 + 255) / 256, 256, 0, stream>>>(blocks_W, wt, 30 * 32768);

    conv1_kernel<<<(N * CH + 255) / 256, 256, 0, stream>>>(inputs, conv1_W, conv1_b,
                                                           x0, hbh0, hbl0, N);

    float* xin = x0;
    float* xout = x1;
    const int gemm_grid = (N + 31) / 32;        // 1563 blocks, 32-row tiles

    for (int i = 0; i < N_LAYERS; ++i) {
        for (int j = 0; j < 2; ++j) {
            int s = i * 2 + j;
            const unsigned short* Wt_s = wt + (size_t)s * 65536;
            const float* b = blocks_b + (size_t)s * CH;
            const unsigned short* ah = (j == 0) ? hbh0 : hbh1;
            const unsigned short* al = (j == 0) ? hbl0 : hbl1;
            unsigned short* oh = (j == 0) ? hbh1 : hbh0;
            unsigned short* ol = (j == 0) ? hbl1 : hbl0;
            const float* resp = (j == 1) ? xin : nullptr;
            float* outp = (j == 1) ? xout : nullptr;
            // fused column-reduce slot: gemm (even i, j=1) feeds avg step (i+1, 0);
            // gemm (odd i, j=0) feeds avg step (i, 1). Slot index = producing layer i.
            float* accp = nullptr;
            if (j == 1 && (i % 2 == 0) && i < 14) accp = acc_base + (size_t)i * CH;
            if (j == 0 && (i % 2 == 1))           accp = acc_base + (size_t)i * CH;
            if (i % 2 == 0) {
                lap_kernel<<<LAP_BLOCKS, 256, 0, stream>>>(row_ptr, col_s, val_s, ah, ph, N);
                gemm_mfma_kernel<<<gemm_grid, 256, 0, stream>>>(ah, al, ph, Wt_s, b,
                                                                resp, outp, oh, ol,
                                                                mask, accp,
                                                                nullptr, denom, nullptr,
                                                                N, 8);
            } else {
                // avg step: bias2 computed inside the gemm from acc slot (i-1+j)
                const float* accv = acc_base + (size_t)(i - 1 + j) * CH;
                const float* Wb = blocks_W + (size_t)s * 256 * CH + 128 * CH;
                gemm_mfma_kernel<<<gemm_grid, 256, 0, stream>>>(ah, al, nullptr, Wt_s, b,
                                                                resp, outp, oh, ol,
                                                                mask, accp,
                                                                accv, denom, Wb,
                                                                N, 4);
            }
        }
        float* t = xin; xin = xout; xout = t;
    }
    // after each layer the elu planes of the layer output land back in slot 0
    final_kernel<<<LAP_BLOCKS, 256, 0, stream>>>(hbh0, hbl0, conv2_W, conv2_b, inputs, out, N);
}

// Round 3
// 1865.061 us; speedup vs baseline: 1.2240x; 1.2240x over previous
//
#include <hip/hip_runtime.h>
#include <hip/hip_bf16.h>

#define N_NODES 50000
#define N_EDGES 600000
#define CH 128
#define N_LAYERS 15
#define LAP_BLOCKS 2048

typedef float f32x4 __attribute__((ext_vector_type(4)));
typedef short s16x8 __attribute__((ext_vector_type(8)));
typedef unsigned short u16x4 __attribute__((ext_vector_type(4)));

#define LD8(p) (*(const s16x8*)(p))

__device__ __forceinline__ float eluf(float v) {
    return v > 0.f ? v : (__expf(v) - 1.f);
}

// float -> bf16 round-to-nearest-even, raw ushort
__device__ __forceinline__ unsigned short f2bf(float f) {
    unsigned int u = __float_as_uint(f);
    unsigned int r = (u + 0x7FFFu + ((u >> 16) & 1u)) >> 16;
    return (unsigned short)r;
}
__device__ __forceinline__ float bf2f(unsigned short h) {
    return __uint_as_float(((unsigned int)h) << 16);
}

// ---------------- conv1: [N,3] @ [3,128] + b ; writes x fp32 + elu planes ----------------
__global__ __launch_bounds__(256) void conv1_kernel(
    const float* __restrict__ in, const float* __restrict__ W1,
    const float* __restrict__ b1, float* __restrict__ x,
    unsigned short* __restrict__ hbh, unsigned short* __restrict__ hbl, int n)
{
    int idx = blockIdx.x * blockDim.x + threadIdx.x;
    if (idx >= n * CH) return;
    int node = idx >> 7;
    int c = idx & 127;
    float o = b1[c]
            + in[(size_t)node * 3 + 0] * W1[0 * CH + c]
            + in[(size_t)node * 3 + 1] * W1[1 * CH + c]
            + in[(size_t)node * 3 + 2] * W1[2 * CH + c];
    x[idx] = o;
    float e = eluf(o);
    unsigned short hi = f2bf(e);
    hbh[idx] = hi;
    hbl[idx] = f2bf(e - bf2f(hi));
}

// ---------------- zero helpers ----------------
__global__ __launch_bounds__(256) void zero_int_kernel(int* __restrict__ p, int n) {
    int i = blockIdx.x * blockDim.x + threadIdx.x;
    if (i < n) p[i] = 0;
}
__global__ __launch_bounds__(256) void zero_float_kernel(float* __restrict__ p, int n) {
    int i = blockIdx.x * blockDim.x + threadIdx.x;
    if (i < n) p[i] = 0.f;
}

// ---------------- CSR build ----------------
__global__ __launch_bounds__(256) void count_kernel(
    const int* __restrict__ row, int* __restrict__ cnt, int e)
{
    int i = blockIdx.x * blockDim.x + threadIdx.x;
    if (i < e) atomicAdd(&cnt[row[i]], 1);
}

__global__ __launch_bounds__(1024) void block_reduce_kernel(
    const int* __restrict__ cnt, int* __restrict__ bsum, int n)
{
    __shared__ int sd[1024];
    int tid = threadIdx.x;
    int i = blockIdx.x * 1024 + tid;
    sd[tid] = (i < n) ? cnt[i] : 0;
    __syncthreads();
    for (int off = 512; off > 0; off >>= 1) {
        if (tid < off) sd[tid] += sd[tid + off];
        __syncthreads();
    }
    if (tid == 0) bsum[blockIdx.x] = sd[0];
}

__global__ __launch_bounds__(64) void scan_small_kernel(
    const int* __restrict__ bsum, int* __restrict__ boff, int nb)
{
    int lane = threadIdx.x;
    int orig = (lane < nb) ? bsum[lane] : 0;
    int v = orig;
#pragma unroll
    for (int d = 1; d < 64; d <<= 1) {
        int t = __shfl_up(v, d, 64);
        if (lane >= d) v += t;
    }
    if (lane < nb) boff[lane] = v - orig;  // exclusive
}

__global__ __launch_bounds__(1024) void block_scan_kernel(
    const int* __restrict__ cnt, const int* __restrict__ boff,
    int* __restrict__ row_ptr, int n)
{
    __shared__ int sd[1024];
    int tid = threadIdx.x;
    int i = blockIdx.x * 1024 + tid;
    sd[tid] = (i < n) ? cnt[i] : 0;
    __syncthreads();
    for (int off = 1; off < 1024; off <<= 1) {
        int t = (tid >= off) ? sd[tid - off] : 0;
        __syncthreads();
        sd[tid] += t;
        __syncthreads();
    }
    if (i < n) row_ptr[i + 1] = sd[tid] + boff[blockIdx.x];
    if (i == 0) row_ptr[0] = 0;
}

// col_s stores byte offset of the gather row start: col * CH * 2 = col << 8
__global__ __launch_bounds__(256) void fill_kernel(
    const int* __restrict__ row, const int* __restrict__ col,
    const float* __restrict__ val, int* __restrict__ cursor,
    const int* __restrict__ row_ptr, int* __restrict__ col_s,
    float* __restrict__ val_s, int e)
{
    int i = blockIdx.x * blockDim.x + threadIdx.x;
    if (i >= e) return;
    int r = row[i];
    int pos = atomicAdd(&cursor[r], 1);
    int dst = row_ptr[r] + pos;
    col_s[dst] = col[i] << 8;
    val_s[dst] = val[i];
}

// ---------------- mask denominator (once per call) ----------------
__global__ __launch_bounds__(256) void mask_sum_kernel(
    const float* __restrict__ mask, float* __restrict__ denom, int n)
{
    __shared__ float sd[256];
    int tid = threadIdx.x;
    float s = 0.f;
    for (int i = blockIdx.x * 256 + tid; i < n; i += gridDim.x * 256) s += mask[i];
    sd[tid] = s;
    __syncthreads();
    for (int off = 128; off > 0; off >>= 1) {
        if (tid < off) sd[tid] += sd[tid + off];
        __syncthreads();
    }
    if (tid == 0) atomicAdd(denom, sd[0]);
}

// ---- W pre-split into MFMA-FRAGMENT-ordered layout:
// Wf[s][plane][chunk c][ntile][lane=q*16+c16][8 shorts] — wave B-fragment loads
// are 16B/lane coalesced straight from L2 (no LDS staging).
__global__ __launch_bounds__(256) void split_w_kernel(
    const float* __restrict__ W, unsigned short* __restrict__ Wf, int total)
{
    int id = blockIdx.x * 256 + threadIdx.x;
    if (id >= total) return;
    int s = id >> 15;
    int rem = id & 32767;
    int k = rem >> 7;                 // 0..255
    int nn = rem & 127;               // col
    float a = W[id];
    unsigned short hi = f2bf(a);
    float r = a - bf2f(hi);
    unsigned short mi = f2bf(r);
    int c   = k >> 5;                 // chunk
    int kin = k & 31;
    int q   = kin >> 3;
    int ko  = kin & 7;
    int nt  = nn >> 4;
    int c16 = nn & 15;
    int lane = q * 16 + c16;
    size_t base = (size_t)s * 65536 + (size_t)c * 4096 + (size_t)nt * 512
                + (size_t)lane * 8 + ko;
    Wf[base]         = hi;
    Wf[base + 32768] = mi;
}

// ---------------- Laplacian: prop[row,:] = sum_e val * hb[col,:]
// PERSISTENT: 2048 blocks; each wave-unit grid-strides over rows.
// cols are pre-scaled byte offsets. Writes single hi bf16 plane.
__global__ __launch_bounds__(256) void lap_kernel(
    const int* __restrict__ rp, const int* __restrict__ cols,
    const float* __restrict__ vals, const unsigned short* __restrict__ hb,
    unsigned short* __restrict__ ph, int n)
{
    int unit = (blockIdx.x * 256 + threadIdx.x) >> 6;    // global wave id
    int lane = threadIdx.x & 63;
    int ch2 = ((((unit & 1) << 6) + lane) << 1);         // byte offset in gather row
    int stride = (LAP_BLOCKS * 4) >> 1;                  // row stride (2 units/row)
    const char* hbase = (const char*)hb;
    for (int row = unit >> 1; row < n; row += stride) {
        int s = rp[row], e = rp[row + 1];
        float acc = 0.f;
        int t = s;
        for (; t + 8 <= e; t += 8) {
            int c0 = cols[t],     c1 = cols[t + 1], c2 = cols[t + 2], c3 = cols[t + 3];
            int c4 = cols[t + 4], c5 = cols[t + 5], c6 = cols[t + 6], c7 = cols[t + 7];
            float v0 = vals[t],     v1 = vals[t + 1], v2 = vals[t + 2], v3 = vals[t + 3];
            float v4 = vals[t + 4], v5 = vals[t + 5], v6 = vals[t + 6], v7 = vals[t + 7];
            float h0 = bf2f(*(const unsigned short*)(hbase + c0 + ch2));
            float h1 = bf2f(*(const unsigned short*)(hbase + c1 + ch2));
            float h2 = bf2f(*(const unsigned short*)(hbase + c2 + ch2));
            float h3 = bf2f(*(const unsigned short*)(hbase + c3 + ch2));
            float h4 = bf2f(*(const unsigned short*)(hbase + c4 + ch2));
            float h5 = bf2f(*(const unsigned short*)(hbase + c5 + ch2));
            float h6 = bf2f(*(const unsigned short*)(hbase + c6 + ch2));
            float h7 = bf2f(*(const unsigned short*)(hbase + c7 + ch2));
            acc += v0 * h0 + v1 * h1 + v2 * h2 + v3 * h3
                 + v4 * h4 + v5 * h5 + v6 * h6 + v7 * h7;
        }
        for (; t + 4 <= e; t += 4) {
            int c0 = cols[t], c1 = cols[t + 1], c2 = cols[t + 2], c3 = cols[t + 3];
            float v0 = vals[t], v1 = vals[t + 1], v2 = vals[t + 2], v3 = vals[t + 3];
            float h0 = bf2f(*(const unsigned short*)(hbase + c0 + ch2));
            float h1 = bf2f(*(const unsigned short*)(hbase + c1 + ch2));
            float h2 = bf2f(*(const unsigned short*)(hbase + c2 + ch2));
            float h3 = bf2f(*(const unsigned short*)(hbase + c3 + ch2));
            acc += v0 * h0 + v1 * h1 + v2 * h2 + v3 * h3;
        }
        for (; t < e; ++t)
            acc += vals[t] * bf2f(*(const unsigned short*)(hbase + cols[t] + ch2));
        ph[row * CH + (ch2 >> 1)] = f2bf(acc);
    }
}

// ---------------- MFMA GEMM: 64-row tile (782 blocks, R1 grid), reg-direct A
// one-chunk-ahead, B direct from L2, FUSED coalesced LDS epilogue:
// acc+bias -> LDS fp32 tile -> single flush pass doing res-add (f32x4 read),
// out store (f32x4), elu, hb u16x4 stores, masked column-sum. All global
// accesses full-line coalesced; one LDS round trip.
__global__ __launch_bounds__(256, 4) void gemm_mfma_kernel(
    const unsigned short* __restrict__ Ah, const unsigned short* __restrict__ Al,
    const unsigned short* __restrict__ Ph,
    const unsigned short* __restrict__ Wf, const float* __restrict__ bias,
    const float* __restrict__ res, float* __restrict__ out,
    unsigned short* __restrict__ hbh, unsigned short* __restrict__ hbl,
    const float* __restrict__ mask, float* __restrict__ accp,
    const float* __restrict__ accv, const float* __restrict__ denom,
    const float* __restrict__ Wb,
    int n, int nch)
{
    __shared__ float tile[64 * 132];              // 33.8 KB padded fp32 tile
    __shared__ float csum[128];
    __shared__ float avg_s[128];
    __shared__ float partial[256];
    __shared__ float bias_s[128];
    const int tid = threadIdx.x;
    const int m_base = blockIdx.x * 64;
    const int wid = tid >> 6;
    const int lane = tid & 63;
    const int wm = wid & 1, wn = wid >> 1;        // wave row-half / col-half
    const int q = lane >> 4, c16 = lane & 15;

    // per-lane A fragment addresses (element offsets; chunk advances by +32)
    const int aoff0 = (m_base + wm * 32 + c16) * CH + q * 8;   // mt=0
    const int aoff1 = aoff0 + 16 * CH;                         // mt=1
    const unsigned short* wf0 = Wf + wn * 2048 + lane * 8;     // B base (col-half)

    f32x4 acc[2][4];
#pragma unroll
    for (int i = 0; i < 2; i++)
#pragma unroll
        for (int j = 0; j < 4; j++) acc[i][j] = (f32x4){0.f, 0.f, 0.f, 0.f};

    // chunk-0 A loads in flight across the bias/avg prologue
    s16x8 cH0 = LD8(Ah + aoff0), cH1 = LD8(Ah + aoff1);
    s16x8 cL0 = LD8(Al + aoff0), cL1 = LD8(Al + aoff1);

    if (tid < 128) {
        bias_s[tid] = bias[tid];
        if (accv) avg_s[tid] = accv[tid] / denom[0];
    }
    __syncthreads();   // bias_s (+avg_s) visible to all waves
    // in-kernel bias2: bias_s += (acc/denom) @ Wb  (avg steps only; block-uniform)
    if (accv) {
        int c = tid & 127;
        int h = tid >> 7;
        float o = 0.f;
#pragma unroll 8
        for (int k = h * 64; k < h * 64 + 64; ++k) o += avg_s[k] * Wb[(size_t)k * CH + c];
        partial[tid] = o;
        __syncthreads();
        if (tid < 128) bias_s[tid] += partial[tid] + partial[tid + 128];
        // visibility to epilogue via the epilogue-start barrier below
    }

    s16x8 pc0, pc1;                                // prop A pipeline regs
    // ---- dense chunks 0..3 (hi+lo A planes, 3 MFMA per tile) ----
#pragma unroll
    for (int ch = 0; ch < 4; ++ch) {
        s16x8 nH0, nH1, nL0, nL1;
        if (ch < 3) {
            nH0 = LD8(Ah + aoff0 + (ch + 1) * 32);
            nH1 = LD8(Ah + aoff1 + (ch + 1) * 32);
            nL0 = LD8(Al + aoff0 + (ch + 1) * 32);
            nL1 = LD8(Al + aoff1 + (ch + 1) * 32);
        } else if (nch > 4) {
            pc0 = LD8(Ph + aoff0);
            pc1 = LD8(Ph + aoff1);
        }
        s16x8 b0[4], b1[4];
        const unsigned short* wp = wf0 + (size_t)ch * 4096;
#pragma unroll
        for (int nt = 0; nt < 4; ++nt) {
            b0[nt] = LD8(wp + nt * 512);
            b1[nt] = LD8(wp + nt * 512 + 32768);
        }
#pragma unroll
        for (int nt = 0; nt < 4; ++nt) {
            f32x4 c0 = acc[0][nt];
            c0 = __builtin_amdgcn_mfma_f32_16x16x32_bf16(cH0, b0[nt], c0, 0, 0, 0);
            c0 = __builtin_amdgcn_mfma_f32_16x16x32_bf16(cH0, b1[nt], c0, 0, 0, 0);
            c0 = __builtin_amdgcn_mfma_f32_16x16x32_bf16(cL0, b0[nt], c0, 0, 0, 0);
            acc[0][nt] = c0;
            f32x4 c1 = acc[1][nt];
            c1 = __builtin_amdgcn_mfma_f32_16x16x32_bf16(cH1, b0[nt], c1, 0, 0, 0);
            c1 = __builtin_amdgcn_mfma_f32_16x16x32_bf16(cH1, b1[nt], c1, 0, 0, 0);
            c1 = __builtin_amdgcn_mfma_f32_16x16x32_bf16(cL1, b0[nt], c1, 0, 0, 0);
            acc[1][nt] = c1;
        }
        if (ch < 3) { cH0 = nH0; cH1 = nH1; cL0 = nL0; cL1 = nL1; }
    }
    // ---- prop chunks 4..7 (hi A plane only, 2 MFMA per tile) ----
    if (nch > 4) {
#pragma unroll
        for (int cc = 0; cc < 4; ++cc) {
            s16x8 np0, np1;
            if (cc < 3) {
                np0 = LD8(Ph + aoff0 + (cc + 1) * 32);
                np1 = LD8(Ph + aoff1 + (cc + 1) * 32);
            }
            s16x8 b0[4], b1[4];
            const unsigned short* wp = wf0 + (size_t)(4 + cc) * 4096;
#pragma unroll
            for (int nt = 0; nt < 4; ++nt) {
                b0[nt] = LD8(wp + nt * 512);
                b1[nt] = LD8(wp + nt * 512 + 32768);
            }
#pragma unroll
            for (int nt = 0; nt < 4; ++nt) {
                f32x4 c0 = acc[0][nt];
                c0 = __builtin_amdgcn_mfma_f32_16x16x32_bf16(pc0, b0[nt], c0, 0, 0, 0);
                c0 = __builtin_amdgcn_mfma_f32_16x16x32_bf16(pc0, b1[nt], c0, 0, 0, 0);
                acc[0][nt] = c0;
                f32x4 c1 = acc[1][nt];
                c1 = __builtin_amdgcn_mfma_f32_16x16x32_bf16(pc1, b0[nt], c1, 0, 0, 0);
                c1 = __builtin_amdgcn_mfma_f32_16x16x32_bf16(pc1, b1[nt], c1, 0, 0, 0);
                acc[1][nt] = c1;
            }
            if (cc < 3) { pc0 = np0; pc1 = np1; }
        }
    }

    // ---- fused epilogue ----
    if (accp && tid < 128) csum[tid] = 0.f;
    __syncthreads();                    // bias_s final, csum zeroed, tile free

    // phase 1: acc + bias -> LDS fp32 tile
#pragma unroll
    for (int mt = 0; mt < 2; ++mt)
#pragma unroll
        for (int nt = 0; nt < 4; ++nt) {
            int col = wn * 64 + nt * 16 + c16;
            float bv = bias_s[col];
            int lrow = wm * 32 + mt * 16 + q * 4;
#pragma unroll
            for (int r = 0; r < 4; ++r)
                tile[(lrow + r) * 132 + col] = acc[mt][nt][r] + bv;
        }
    __syncthreads();

    // phase 2: coalesced flush (res add, out store, elu, hb stores, col-sum)
    float colsum[4] = {0.f, 0.f, 0.f, 0.f};
    const int c4 = (tid & 31) << 2;
    for (int e4 = tid; e4 < 2048; e4 += 256) {
        int row = e4 >> 5;
        int grow = m_base + row;
        if (grow < n) {
            f32x4 v = *(const f32x4*)&tile[row * 132 + c4];
            size_t o4 = (size_t)grow * CH + c4;
            if (res) {
                f32x4 rv = *(const f32x4*)(res + o4);
                v = v + rv;
            }
            if (out) *(f32x4*)(out + o4) = v;
            float e0 = eluf(v[0]), e1 = eluf(v[1]), e2 = eluf(v[2]), e3 = eluf(v[3]);
            unsigned short h0 = f2bf(e0), h1 = f2bf(e1), h2 = f2bf(e2), h3 = f2bf(e3);
            u16x4 hv = {h0, h1, h2, h3};
            u16x4 lv = {f2bf(e0 - bf2f(h0)), f2bf(e1 - bf2f(h1)),
                        f2bf(e2 - bf2f(h2)), f2bf(e3 - bf2f(h3))};
            *(u16x4*)(hbh + o4) = hv;
            *(u16x4*)(hbl + o4) = lv;
            if (accp) {
                float mk = mask[grow];
                colsum[0] += mk * e0; colsum[1] += mk * e1;
                colsum[2] += mk * e2; colsum[3] += mk * e3;
            }
        }
    }
    if (accp) {
#pragma unroll
        for (int jj = 0; jj < 4; ++jj) atomicAdd(&csum[c4 + jj], colsum[jj]);
        __syncthreads();
        if (tid < 128) atomicAdd(&accp[tid], csum[tid]);
    }
}

// ---------------- final head: out[n] = elu(x) @ W2 + b2 + inputs[n,0]; persistent ----------------
__global__ __launch_bounds__(256) void final_kernel(
    const unsigned short* __restrict__ hh, const unsigned short* __restrict__ hl,
    const float* __restrict__ W2, const float* __restrict__ b2,
    const float* __restrict__ in, float* __restrict__ out, int n)
{
    int wave = (blockIdx.x * blockDim.x + threadIdx.x) >> 6;
    int lane = threadIdx.x & 63;
    int stride = gridDim.x * 4;
    for (int row = wave; row < n; row += stride) {
        size_t i1 = (size_t)row * CH + lane;
        size_t i2 = i1 + 64;
        float v = (bf2f(hh[i1]) + bf2f(hl[i1])) * W2[lane]
                + (bf2f(hh[i2]) + bf2f(hl[i2])) * W2[64 + lane];
#pragma unroll
        for (int off = 32; off > 0; off >>= 1) v += __shfl_down(v, off, 64);
        if (lane == 0) out[row] = v + b2[0] + in[(size_t)row * 3];
    }
}

extern "C" void kernel_launch(void* const* d_in, const int* in_sizes, int n_in,
                              void* d_out, int out_size, void* d_ws, size_t ws_size,
                              hipStream_t stream)
{
    const int*   L_row   = (const int*)d_in[0];
    const int*   L_col   = (const int*)d_in[1];
    const float* L_val   = (const float*)d_in[2];
    const float* mask    = (const float*)d_in[3];
    const float* inputs  = (const float*)d_in[4];
    const float* conv1_W = (const float*)d_in[5];
    const float* conv1_b = (const float*)d_in[6];
    const float* blocks_W = (const float*)d_in[7];
    const float* blocks_b = (const float*)d_in[8];
    const float* conv2_W = (const float*)d_in[9];
    const float* conv2_b = (const float*)d_in[10];
    float* out = (float*)d_out;

    const int N = N_NODES, E = N_EDGES;
    const size_t NF = (size_t)N * CH;
    const int NPAD = 50048;
    const int NB = (N + 1023) / 1024;

    float* ws = (float*)d_ws;
    float* x0 = ws;                                   // fp32 residual chain (2 slots)
    float* x1 = x0 + NF;
    unsigned short* hbh0 = (unsigned short*)(x1 + NF);  // elu planes, slot 0
    unsigned short* hbl0 = hbh0 + NF;
    unsigned short* hbh1 = hbl0 + NF;                   // elu planes, slot 1
    unsigned short* hbl1 = hbh1 + NF;
    unsigned short* ph   = hbl1 + NF;                   // prop hi plane
    int* cnt     = (int*)(ph + 2 * NF);                 // (gap keeps prior layout size)
    int* cursor  = cnt + NPAD;
    int* row_ptr = cursor + NPAD;
    int* bsum    = row_ptr + NPAD;
    int* boff    = bsum + 64;
    int* col_s   = boff + 64;
    float* val_s = (float*)(col_s + E);
    float* acc_base = val_s + E;                        // 14 slots x 128
    float* denom    = acc_base + 14 * CH;
    unsigned short* wt = (unsigned short*)(denom + 16 + 160);  // 30*65536 shorts (frag order)

    zero_int_kernel<<<(2 * NPAD + 255) / 256, 256, 0, stream>>>(cnt, 2 * NPAD);
    zero_float_kernel<<<(14 * CH + 16 + 255) / 256, 256, 0, stream>>>(acc_base, 14 * CH + 16);
    count_kernel<<<(E + 255) / 256, 256, 0, stream>>>(L_row, cnt, E);
    block_reduce_kernel<<<NB, 1024, 0, stream>>>(cnt, bsum, N);
    scan_small_kernel<<<1, 64, 0, stream>>>(bsum, boff, NB);
    block_scan_kernel<<<NB, 1024, 0, stream>>>(cnt, boff, row_ptr, N);
    fill_kernel<<<(E + 255) / 256, 256, 0, stream>>>(L_row, L_col, L_val, cursor,
                                                     row_ptr, col_s, val_s, E);
    mask_sum_kernel<<<64, 256, 0, stream>>>(mask, denom, N);
    split_w_kernel<<<(30 * 32768 + 255) / 256, 256, 0, stream>>>(blocks_W, wt, 30 * 32768);

    conv1_kernel<<<(N * CH + 255) / 256, 256, 0, stream>>>(inputs, conv1_W, conv1_b,
                                                           x0, hbh0, hbl0, N);

    float* xin = x0;
    float* xout = x1;
    const int gemm_grid = (N + 63) / 64;        // 782 blocks, 64-row tiles

    for (int i = 0; i < N_LAYERS; ++i) {
        for (int j = 0; j < 2; ++j) {
            int s = i * 2 + j;
            const unsigned short* Wt_s = wt + (size_t)s * 65536;
            const float* b = blocks_b + (size_t)s * CH;
            const unsigned short* ah = (j == 0) ? hbh0 : hbh1;
            const unsigned short* al = (j == 0) ? hbl0 : hbl1;
            unsigned short* oh = (j == 0) ? hbh1 : hbh0;
            unsigned short* ol = (j == 0) ? hbl1 : hbl0;
            const float* resp = (j == 1) ? xin : nullptr;
            float* outp = (j == 1) ? xout : nullptr;
            // fused column-reduce slot: gemm (even i, j=1) feeds avg step (i+1, 0);
            // gemm (odd i, j=0) feeds avg step (i, 1). Slot index = producing layer i.
            float* accp = nullptr;
            if (j == 1 && (i % 2 == 0) && i < 14) accp = acc_base + (size_t)i * CH;
            if (j == 0 && (i % 2 == 1))           accp = acc_base + (size_t)i * CH;
            if (i % 2 == 0) {
                lap_kernel<<<LAP_BLOCKS, 256, 0, stream>>>(row_ptr, col_s, val_s, ah, ph, N);
                gemm_mfma_kernel<<<gemm_grid, 256, 0, stream>>>(ah, al, ph, Wt_s, b,
                                                                resp, outp, oh, ol,
                                                                mask, accp,
                                                                nullptr, denom, nullptr,
                                                                N, 8);
            } else {
                // avg step: bias2 computed inside the gemm from acc slot (i-1+j)
                const float* accv = acc_base + (size_t)(i - 1 + j) * CH;
                const float* Wb = blocks_W + (size_t)s * 256 * CH + 128 * CH;
                gemm_mfma_kernel<<<gemm_grid, 256, 0, stream>>>(ah, al, nullptr, Wt_s, b,
                                                                resp, outp, oh, ol,
                                                                mask, accp,
                                                                accv, denom, Wb,
                                                                N, 4);
            }
        }
        float* t = xin; xin = xout; xout = t;
    }
    // after each layer the elu planes of the layer output land back in slot 0
    final_kernel<<<LAP_BLOCKS, 256, 0, stream>>>(hbh0, hbl0, conv2_W, conv2_b, inputs, out, N);
}

// Round 5
// 1805.006 us; speedup vs baseline: 1.2647x; 1.0333x over previous
//
#include <hip/hip_runtime.h>
#include <hip/hip_bf16.h>

#define N_NODES 50000
#define N_EDGES 600000
#define CH 128
#define N_LAYERS 15
#define LAP_BLOCKS 2048

typedef float f32x4 __attribute__((ext_vector_type(4)));
typedef short s16x8 __attribute__((ext_vector_type(8)));
typedef unsigned short u16x4 __attribute__((ext_vector_type(4)));

#define LD8(p) (*(const s16x8*)(p))

__device__ __forceinline__ float eluf(float v) {
    return v > 0.f ? v : (__expf(v) - 1.f);
}

// float -> bf16 round-to-nearest-even, raw ushort
__device__ __forceinline__ unsigned short f2bf(float f) {
    unsigned int u = __float_as_uint(f);
    unsigned int r = (u + 0x7FFFu + ((u >> 16) & 1u)) >> 16;
    return (unsigned short)r;
}
__device__ __forceinline__ float bf2f(unsigned short h) {
    return __uint_as_float(((unsigned int)h) << 16);
}

// async global->LDS, 16B per lane (dest must be linear: base + lane*16)
__device__ __forceinline__ void gload_lds16(const unsigned short* g, unsigned short* l) {
    __builtin_amdgcn_global_load_lds(
        (const __attribute__((address_space(1))) unsigned int*)g,
        (__attribute__((address_space(3))) unsigned int*)l, 16, 0, 0);
}

// ---------------- conv1: [N,3] @ [3,128] + b ; writes x fp32 + elu planes ----------------
__global__ __launch_bounds__(256) void conv1_kernel(
    const float* __restrict__ in, const float* __restrict__ W1,
    const float* __restrict__ b1, float* __restrict__ x,
    unsigned short* __restrict__ hbh, unsigned short* __restrict__ hbl, int n)
{
    int idx = blockIdx.x * blockDim.x + threadIdx.x;
    if (idx >= n * CH) return;
    int node = idx >> 7;
    int c = idx & 127;
    float o = b1[c]
            + in[(size_t)node * 3 + 0] * W1[0 * CH + c]
            + in[(size_t)node * 3 + 1] * W1[1 * CH + c]
            + in[(size_t)node * 3 + 2] * W1[2 * CH + c];
    x[idx] = o;
    float e = eluf(o);
    unsigned short hi = f2bf(e);
    hbh[idx] = hi;
    hbl[idx] = f2bf(e - bf2f(hi));
}

// ---------------- zero helpers ----------------
__global__ __launch_bounds__(256) void zero_int_kernel(int* __restrict__ p, int n) {
    int i = blockIdx.x * blockDim.x + threadIdx.x;
    if (i < n) p[i] = 0;
}
__global__ __launch_bounds__(256) void zero_float_kernel(float* __restrict__ p, int n) {
    int i = blockIdx.x * blockDim.x + threadIdx.x;
    if (i < n) p[i] = 0.f;
}

// ---------------- CSR build ----------------
__global__ __launch_bounds__(256) void count_kernel(
    const int* __restrict__ row, int* __restrict__ cnt, int e)
{
    int i = blockIdx.x * blockDim.x + threadIdx.x;
    if (i < e) atomicAdd(&cnt[row[i]], 1);
}

__global__ __launch_bounds__(1024) void block_reduce_kernel(
    const int* __restrict__ cnt, int* __restrict__ bsum, int n)
{
    __shared__ int sd[1024];
    int tid = threadIdx.x;
    int i = blockIdx.x * 1024 + tid;
    sd[tid] = (i < n) ? cnt[i] : 0;
    __syncthreads();
    for (int off = 512; off > 0; off >>= 1) {
        if (tid < off) sd[tid] += sd[tid + off];
        __syncthreads();
    }
    if (tid == 0) bsum[blockIdx.x] = sd[0];
}

__global__ __launch_bounds__(64) void scan_small_kernel(
    const int* __restrict__ bsum, int* __restrict__ boff, int nb)
{
    int lane = threadIdx.x;
    int orig = (lane < nb) ? bsum[lane] : 0;
    int v = orig;
#pragma unroll
    for (int d = 1; d < 64; d <<= 1) {
        int t = __shfl_up(v, d, 64);
        if (lane >= d) v += t;
    }
    if (lane < nb) boff[lane] = v - orig;  // exclusive
}

__global__ __launch_bounds__(1024) void block_scan_kernel(
    const int* __restrict__ cnt, const int* __restrict__ boff,
    int* __restrict__ row_ptr, int n)
{
    __shared__ int sd[1024];
    int tid = threadIdx.x;
    int i = blockIdx.x * 1024 + tid;
    sd[tid] = (i < n) ? cnt[i] : 0;
    __syncthreads();
    for (int off = 1; off < 1024; off <<= 1) {
        int t = (tid >= off) ? sd[tid - off] : 0;
        __syncthreads();
        sd[tid] += t;
        __syncthreads();
    }
    if (i < n) row_ptr[i + 1] = sd[tid] + boff[blockIdx.x];
    if (i == 0) row_ptr[0] = 0;
}

// col_s stores byte offset of the gather row start: col * CH * 2 = col << 8
__global__ __launch_bounds__(256) void fill_kernel(
    const int* __restrict__ row, const int* __restrict__ col,
    const float* __restrict__ val, int* __restrict__ cursor,
    const int* __restrict__ row_ptr, int* __restrict__ col_s,
    float* __restrict__ val_s, int e)
{
    int i = blockIdx.x * blockDim.x + threadIdx.x;
    if (i >= e) return;
    int r = row[i];
    int pos = atomicAdd(&cursor[r], 1);
    int dst = row_ptr[r] + pos;
    col_s[dst] = col[i] << 8;
    val_s[dst] = val[i];
}

// ---------------- mask denominator (once per call) ----------------
__global__ __launch_bounds__(256) void mask_sum_kernel(
    const float* __restrict__ mask, float* __restrict__ denom, int n)
{
    __shared__ float sd[256];
    int tid = threadIdx.x;
    float s = 0.f;
    for (int i = blockIdx.x * 256 + tid; i < n; i += gridDim.x * 256) s += mask[i];
    sd[tid] = s;
    __syncthreads();
    for (int off = 128; off > 0; off >>= 1) {
        if (tid < off) sd[tid] += sd[tid + off];
        __syncthreads();
    }
    if (tid == 0) atomicAdd(denom, sd[0]);
}

// ---- W pre-split into MFMA-FRAGMENT-ordered layout:
// Wf[s][plane][chunk c][ntile][lane=q*16+c16][8 shorts] — wave B-fragment loads
// are 16B/lane coalesced straight from L2 (no LDS staging).
__global__ __launch_bounds__(256) void split_w_kernel(
    const float* __restrict__ W, unsigned short* __restrict__ Wf, int total)
{
    int id = blockIdx.x * 256 + threadIdx.x;
    if (id >= total) return;
    int s = id >> 15;
    int rem = id & 32767;
    int k = rem >> 7;                 // 0..255
    int nn = rem & 127;               // col
    float a = W[id];
    unsigned short hi = f2bf(a);
    float r = a - bf2f(hi);
    unsigned short mi = f2bf(r);
    int c   = k >> 5;                 // chunk
    int kin = k & 31;
    int q   = kin >> 3;
    int ko  = kin & 7;
    int nt  = nn >> 4;
    int c16 = nn & 15;
    int lane = q * 16 + c16;
    size_t base = (size_t)s * 65536 + (size_t)c * 4096 + (size_t)nt * 512
                + (size_t)lane * 8 + ko;
    Wf[base]         = hi;
    Wf[base + 32768] = mi;
}

// ---------------- Laplacian: prop[row,:] = sum_e val * hb[col,:]
// PERSISTENT: 2048 blocks; each wave-unit grid-strides over rows.
// cols are pre-scaled byte offsets. Writes single hi bf16 plane.
__global__ __launch_bounds__(256) void lap_kernel(
    const int* __restrict__ rp, const int* __restrict__ cols,
    const float* __restrict__ vals, const unsigned short* __restrict__ hb,
    unsigned short* __restrict__ ph, int n)
{
    int unit = (blockIdx.x * 256 + threadIdx.x) >> 6;    // global wave id
    int lane = threadIdx.x & 63;
    int ch2 = ((((unit & 1) << 6) + lane) << 1);         // byte offset in gather row
    int stride = (LAP_BLOCKS * 4) >> 1;                  // row stride (2 units/row)
    const char* hbase = (const char*)hb;
    for (int row = unit >> 1; row < n; row += stride) {
        int s = rp[row], e = rp[row + 1];
        float acc = 0.f;
        int t = s;
        for (; t + 8 <= e; t += 8) {
            int c0 = cols[t],     c1 = cols[t + 1], c2 = cols[t + 2], c3 = cols[t + 3];
            int c4 = cols[t + 4], c5 = cols[t + 5], c6 = cols[t + 6], c7 = cols[t + 7];
            float v0 = vals[t],     v1 = vals[t + 1], v2 = vals[t + 2], v3 = vals[t + 3];
            float v4 = vals[t + 4], v5 = vals[t + 5], v6 = vals[t + 6], v7 = vals[t + 7];
            float h0 = bf2f(*(const unsigned short*)(hbase + c0 + ch2));
            float h1 = bf2f(*(const unsigned short*)(hbase + c1 + ch2));
            float h2 = bf2f(*(const unsigned short*)(hbase + c2 + ch2));
            float h3 = bf2f(*(const unsigned short*)(hbase + c3 + ch2));
            float h4 = bf2f(*(const unsigned short*)(hbase + c4 + ch2));
            float h5 = bf2f(*(const unsigned short*)(hbase + c5 + ch2));
            float h6 = bf2f(*(const unsigned short*)(hbase + c6 + ch2));
            float h7 = bf2f(*(const unsigned short*)(hbase + c7 + ch2));
            acc += v0 * h0 + v1 * h1 + v2 * h2 + v3 * h3
                 + v4 * h4 + v5 * h5 + v6 * h6 + v7 * h7;
        }
        for (; t + 4 <= e; t += 4) {
            int c0 = cols[t], c1 = cols[t + 1], c2 = cols[t + 2], c3 = cols[t + 3];
            float v0 = vals[t], v1 = vals[t + 1], v2 = vals[t + 2], v3 = vals[t + 3];
            float h0 = bf2f(*(const unsigned short*)(hbase + c0 + ch2));
            float h1 = bf2f(*(const unsigned short*)(hbase + c1 + ch2));
            float h2 = bf2f(*(const unsigned short*)(hbase + c2 + ch2));
            float h3 = bf2f(*(const unsigned short*)(hbase + c3 + ch2));
            acc += v0 * h0 + v1 * h1 + v2 * h2 + v3 * h3;
        }
        for (; t < e; ++t)
            acc += vals[t] * bf2f(*(const unsigned short*)(hbase + cols[t] + ch2));
        ph[row * CH + (ch2 >> 1)] = f2bf(acc);
    }
}

// ---------------- MFMA GEMM: 64-row tile, 782 blocks (all co-resident).
// MLP fix: ALL A planes (hi/lo/prop) staged to LDS via 8-12 back-to-back
// global_load_lds per thread (no VGPR cost, ~12KB in flight per wave vs
// the ~190B of the reg-direct version -> latency-bound 1.6 TB/s measured).
// Staging reads each 256B row exactly once, coalesced. XOR slot-swizzle
// (slot ^= row&7) applied on BOTH the staging source addr and the ds_read
// (rule 21) kills the stride-256B 16-way bank conflict. B frags reg-direct
// from L2, pipelined one chunk ahead. Epilogue: fp32 tile OVERLAYS the dead
// A-staging LDS; coalesced f32x4/u16x4 flush (R3, validated).
template<int NCH>
__global__ __launch_bounds__(256, 4) void gemm_mfma_kernel(
    const unsigned short* __restrict__ Ah, const unsigned short* __restrict__ Al,
    const unsigned short* __restrict__ Ph,
    const unsigned short* __restrict__ Wf, const float* __restrict__ bias,
    const float* __restrict__ res, float* __restrict__ out,
    unsigned short* __restrict__ hbh, unsigned short* __restrict__ hbl,
    const float* __restrict__ mask, float* __restrict__ accp,
    const float* __restrict__ accv, const float* __restrict__ denom,
    const float* __restrict__ Wb,
    int n)
{
    constexpr int NPLANES = (NCH > 4) ? 3 : 2;
    constexpr int ASB = NPLANES * 64 * 128 * 2;            // staged A bytes
    constexpr int TILEB = 64 * 132 * 4;                    // epilogue tile bytes
    constexpr int SMB = (ASB > TILEB) ? ASB : TILEB;
    __shared__ __align__(16) char smem[SMB];
    unsigned short* as = (unsigned short*)smem;            // [plane][row*128 + swslot*8 + k]
    float* tile = (float*)smem;                            // epilogue overlay
    __shared__ float csum[128];
    __shared__ float partial[256];
    __shared__ float bias_s[128];

    const int tid = threadIdx.x;
    const int m_base = blockIdx.x * 64;

    // ---- stage A planes (swizzled source, linear LDS dest = base + tid*16B) ----
    {
        const int lr = tid >> 4;          // row within 16-row group
        const int slot = tid & 15;        // 16B slot within the 256B row
#pragma unroll
        for (int k = 0; k < 4; ++k) {
            int row = k * 16 + lr;
            int ss = (slot ^ (row & 7)) * 8;               // swizzled source slot
            size_t g = (size_t)(m_base + row) * CH + ss;
            gload_lds16(Ah + g, as + k * 2048 + tid * 8);
            gload_lds16(Al + g, as + 8192 + k * 2048 + tid * 8);
        }
        if (NCH > 4) {
#pragma unroll
            for (int k = 0; k < 4; ++k) {
                int row = k * 16 + lr;
                int ss = (slot ^ (row & 7)) * 8;
                gload_lds16(Ph + (size_t)(m_base + row) * CH + ss,
                            as + 16384 + k * 2048 + tid * 8);
            }
        }
    }

    const int wid = tid >> 6;
    const int lane = tid & 63;
    const int wm = wid & 1, wn = wid >> 1;        // wave row-half / col-half
    const int q = lane >> 4, c16 = lane & 15;
    const int lr0 = wm * 32 + c16;                // mt=0 local row
    const int lr1 = lr0 + 16;                     // mt=1 (same low-3 bits)
    const int xr = lr0 & 7;                       // swizzle key (same for lr1)
    const unsigned short* wf0 = Wf + wn * 2048 + lane * 8;   // B base (col-half)

    f32x4 acc[2][4];
#pragma unroll
    for (int i = 0; i < 2; i++)
#pragma unroll
        for (int j = 0; j < 4; j++) acc[i][j] = (f32x4){0.f, 0.f, 0.f, 0.f};

    // B chunk-0 loads in flight across the bias/avg prologue
    s16x8 b0[4], b1[4];
#pragma unroll
    for (int nt = 0; nt < 4; ++nt) {
        b0[nt] = LD8(wf0 + nt * 512);
        b1[nt] = LD8(wf0 + nt * 512 + 32768);
    }

    if (tid < 128) bias_s[tid] = bias[tid];
    // avg-step bias2 GEMV straight from global (no LDS, no early barrier):
    // partial = rden * sum_k accv[k] * Wb[k,c]
    if (accv) {
        float rden = 1.f / denom[0];
        int c = tid & 127;
        int h = tid >> 7;
        float o = 0.f;
#pragma unroll 8
        for (int k = h * 64; k < h * 64 + 64; ++k) o += accv[k] * Wb[(size_t)k * CH + c];
        partial[tid] = o * rden;
    }
    __syncthreads();   // drains global_load_lds (A staged) + partial/bias_s visible
    if (accv && tid < 128) bias_s[tid] += partial[tid] + partial[tid + 128];
    // (bias_s final value visible to all waves via the post-compute barrier)

    // ---- dense chunks 0..3 (hi+lo A planes, 3 MFMA per tile), B one-ahead ----
#pragma unroll
    for (int ch = 0; ch < 4; ++ch) {
        s16x8 nb0[4], nb1[4];
        if (ch < NCH - 1) {
            const unsigned short* nwp = wf0 + (size_t)(ch + 1) * 4096;
#pragma unroll
            for (int nt = 0; nt < 4; ++nt) {
                nb0[nt] = LD8(nwp + nt * 512);
                nb1[nt] = LD8(nwp + nt * 512 + 32768);
            }
        }
        const int sl = (((ch * 4 + q) ^ xr) << 3);
        s16x8 aH0 = LD8(as + lr0 * 128 + sl);
        s16x8 aH1 = LD8(as + lr1 * 128 + sl);
        s16x8 aL0 = LD8(as + 8192 + lr0 * 128 + sl);
        s16x8 aL1 = LD8(as + 8192 + lr1 * 128 + sl);
#pragma unroll
        for (int nt = 0; nt < 4; ++nt) {
            f32x4 c0 = acc[0][nt];
            c0 = __builtin_amdgcn_mfma_f32_16x16x32_bf16(aH0, b0[nt], c0, 0, 0, 0);
            c0 = __builtin_amdgcn_mfma_f32_16x16x32_bf16(aH0, b1[nt], c0, 0, 0, 0);
            c0 = __builtin_amdgcn_mfma_f32_16x16x32_bf16(aL0, b0[nt], c0, 0, 0, 0);
            acc[0][nt] = c0;
            f32x4 c1 = acc[1][nt];
            c1 = __builtin_amdgcn_mfma_f32_16x16x32_bf16(aH1, b0[nt], c1, 0, 0, 0);
            c1 = __builtin_amdgcn_mfma_f32_16x16x32_bf16(aH1, b1[nt], c1, 0, 0, 0);
            c1 = __builtin_amdgcn_mfma_f32_16x16x32_bf16(aL1, b0[nt], c1, 0, 0, 0);
            acc[1][nt] = c1;
        }
        if (ch < NCH - 1) {
#pragma unroll
            for (int nt = 0; nt < 4; ++nt) { b0[nt] = nb0[nt]; b1[nt] = nb1[nt]; }
        }
    }
    // ---- prop chunks 4..7 (hi A plane only, 2 MFMA per tile) ----
    if (NCH > 4) {
#pragma unroll
        for (int cc = 0; cc < 4; ++cc) {
            s16x8 nb0[4], nb1[4];
            if (cc < 3) {
                const unsigned short* nwp = wf0 + (size_t)(5 + cc) * 4096;
#pragma unroll
                for (int nt = 0; nt < 4; ++nt) {
                    nb0[nt] = LD8(nwp + nt * 512);
                    nb1[nt] = LD8(nwp + nt * 512 + 32768);
                }
            }
            const int sl = (((cc * 4 + q) ^ xr) << 3);
            s16x8 p0 = LD8(as + 16384 + lr0 * 128 + sl);
            s16x8 p1 = LD8(as + 16384 + lr1 * 128 + sl);
#pragma unroll
            for (int nt = 0; nt < 4; ++nt) {
                f32x4 c0 = acc[0][nt];
                c0 = __builtin_amdgcn_mfma_f32_16x16x32_bf16(p0, b0[nt], c0, 0, 0, 0);
                c0 = __builtin_amdgcn_mfma_f32_16x16x32_bf16(p0, b1[nt], c0, 0, 0, 0);
                acc[0][nt] = c0;
                f32x4 c1 = acc[1][nt];
                c1 = __builtin_amdgcn_mfma_f32_16x16x32_bf16(p1, b0[nt], c1, 0, 0, 0);
                c1 = __builtin_amdgcn_mfma_f32_16x16x32_bf16(p1, b1[nt], c1, 0, 0, 0);
                acc[1][nt] = c1;
            }
            if (cc < 3) {
#pragma unroll
                for (int nt = 0; nt < 4; ++nt) { b0[nt] = nb0[nt]; b1[nt] = nb1[nt]; }
            }
        }
    }

    // ---- fused epilogue (tile overlays the dead A staging) ----
    if (accp && tid < 128) csum[tid] = 0.f;
    __syncthreads();            // As reads done -> overlay safe; bias_s final

    // phase 1: acc + bias -> LDS fp32 tile
#pragma unroll
    for (int mt = 0; mt < 2; ++mt)
#pragma unroll
        for (int nt = 0; nt < 4; ++nt) {
            int col = wn * 64 + nt * 16 + c16;
            float bv = bias_s[col];
            int lrow = wm * 32 + mt * 16 + q * 4;
#pragma unroll
            for (int r = 0; r < 4; ++r)
                tile[(lrow + r) * 132 + col] = acc[mt][nt][r] + bv;
        }
    __syncthreads();

    // phase 2: coalesced flush (res add, out store, elu, hb stores, col-sum)
    float colsum[4] = {0.f, 0.f, 0.f, 0.f};
    const int c4 = (tid & 31) << 2;
    for (int e4 = tid; e4 < 2048; e4 += 256) {
        int row = e4 >> 5;
        int grow = m_base + row;
        if (grow < n) {
            f32x4 v = *(const f32x4*)&tile[row * 132 + c4];
            size_t o4 = (size_t)grow * CH + c4;
            if (res) {
                f32x4 rv = *(const f32x4*)(res + o4);
                v = v + rv;
            }
            if (out) *(f32x4*)(out + o4) = v;
            float e0 = eluf(v[0]), e1 = eluf(v[1]), e2 = eluf(v[2]), e3 = eluf(v[3]);
            unsigned short h0 = f2bf(e0), h1 = f2bf(e1), h2 = f2bf(e2), h3 = f2bf(e3);
            u16x4 hv = {h0, h1, h2, h3};
            u16x4 lv = {f2bf(e0 - bf2f(h0)), f2bf(e1 - bf2f(h1)),
                        f2bf(e2 - bf2f(h2)), f2bf(e3 - bf2f(h3))};
            *(u16x4*)(hbh + o4) = hv;
            *(u16x4*)(hbl + o4) = lv;
            if (accp) {
                float mk = mask[grow];
                colsum[0] += mk * e0; colsum[1] += mk * e1;
                colsum[2] += mk * e2; colsum[3] += mk * e3;
            }
        }
    }
    if (accp) {
#pragma unroll
        for (int jj = 0; jj < 4; ++jj) atomicAdd(&csum[c4 + jj], colsum[jj]);
        __syncthreads();
        if (tid < 128) atomicAdd(&accp[tid], csum[tid]);
    }
}

// ---------------- final head: out[n] = elu(x) @ W2 + b2 + inputs[n,0]; persistent ----------------
__global__ __launch_bounds__(256) void final_kernel(
    const unsigned short* __restrict__ hh, const unsigned short* __restrict__ hl,
    const float* __restrict__ W2, const float* __restrict__ b2,
    const float* __restrict__ in, float* __restrict__ out, int n)
{
    int wave = (blockIdx.x * blockDim.x + threadIdx.x) >> 6;
    int lane = threadIdx.x & 63;
    int stride = gridDim.x * 4;
    for (int row = wave; row < n; row += stride) {
        size_t i1 = (size_t)row * CH + lane;
        size_t i2 = i1 + 64;
        float v = (bf2f(hh[i1]) + bf2f(hl[i1])) * W2[lane]
                + (bf2f(hh[i2]) + bf2f(hl[i2])) * W2[64 + lane];
#pragma unroll
        for (int off = 32; off > 0; off >>= 1) v += __shfl_down(v, off, 64);
        if (lane == 0) out[row] = v + b2[0] + in[(size_t)row * 3];
    }
}

extern "C" void kernel_launch(void* const* d_in, const int* in_sizes, int n_in,
                              void* d_out, int out_size, void* d_ws, size_t ws_size,
                              hipStream_t stream)
{
    const int*   L_row   = (const int*)d_in[0];
    const int*   L_col   = (const int*)d_in[1];
    const float* L_val   = (const float*)d_in[2];
    const float* mask    = (const float*)d_in[3];
    const float* inputs  = (const float*)d_in[4];
    const float* conv1_W = (const float*)d_in[5];
    const float* conv1_b = (const float*)d_in[6];
    const float* blocks_W = (const float*)d_in[7];
    const float* blocks_b = (const float*)d_in[8];
    const float* conv2_W = (const float*)d_in[9];
    const float* conv2_b = (const float*)d_in[10];
    float* out = (float*)d_out;

    const int N = N_NODES, E = N_EDGES;
    const size_t NF = (size_t)N * CH;
    const int NPAD = 50048;
    const int NB = (N + 1023) / 1024;

    float* ws = (float*)d_ws;
    float* x0 = ws;                                   // fp32 residual chain (2 slots)
    float* x1 = x0 + NF;
    unsigned short* hbh0 = (unsigned short*)(x1 + NF);  // elu planes, slot 0
    unsigned short* hbl0 = hbh0 + NF;
    unsigned short* hbh1 = hbl0 + NF;                   // elu planes, slot 1
    unsigned short* hbl1 = hbh1 + NF;
    unsigned short* ph   = hbl1 + NF;                   // prop hi plane
    int* cnt     = (int*)(ph + 2 * NF);                 // (gap keeps prior layout size)
    int* cursor  = cnt + NPAD;
    int* row_ptr = cursor + NPAD;
    int* bsum    = row_ptr + NPAD;
    int* boff    = bsum + 64;
    int* col_s   = boff + 64;
    float* val_s = (float*)(col_s + E);
    float* acc_base = val_s + E;                        // 14 slots x 128
    float* denom    = acc_base + 14 * CH;
    unsigned short* wt = (unsigned short*)(denom + 16 + 160);  // 30*65536 shorts (frag order)

    zero_int_kernel<<<(2 * NPAD + 255) / 256, 256, 0, stream>>>(cnt, 2 * NPAD);
    zero_float_kernel<<<(14 * CH + 16 + 255) / 256, 256, 0, stream>>>(acc_base, 14 * CH + 16);
    count_kernel<<<(E + 255) / 256, 256, 0, stream>>>(L_row, cnt, E);
    block_reduce_kernel<<<NB, 1024, 0, stream>>>(cnt, bsum, N);
    scan_small_kernel<<<1, 64, 0, stream>>>(bsum, boff, NB);
    block_scan_kernel<<<NB, 1024, 0, stream>>>(cnt, boff, row_ptr, N);
    fill_kernel<<<(E + 255) / 256, 256, 0, stream>>>(L_row, L_col, L_val, cursor,
                                                     row_ptr, col_s, val_s, E);
    mask_sum_kernel<<<64, 256, 0, stream>>>(mask, denom, N);
    split_w_kernel<<<(30 * 32768 + 255) / 256, 256, 0, stream>>>(blocks_W, wt, 30 * 32768);

    conv1_kernel<<<(N * CH + 255) / 256, 256, 0, stream>>>(inputs, conv1_W, conv1_b,
                                                           x0, hbh0, hbl0, N);

    float* xin = x0;
    float* xout = x1;
    const int gemm_grid = (N + 63) / 64;        // 782 blocks, 64-row tiles

    for (int i = 0; i < N_LAYERS; ++i) {
        for (int j = 0; j < 2; ++j) {
            int s = i * 2 + j;
            const unsigned short* Wt_s = wt + (size_t)s * 65536;
            const float* b = blocks_b + (size_t)s * CH;
            const unsigned short* ah = (j == 0) ? hbh0 : hbh1;
            const unsigned short* al = (j == 0) ? hbl0 : hbl1;
            unsigned short* oh = (j == 0) ? hbh1 : hbh0;
            unsigned short* ol = (j == 0) ? hbl1 : hbl0;
            const float* resp = (j == 1) ? xin : nullptr;
            float* outp = (j == 1) ? xout : nullptr;
            // fused column-reduce slot: gemm (even i, j=1) feeds avg step (i+1, 0);
            // gemm (odd i, j=0) feeds avg step (i, 1). Slot index = producing layer i.
            float* accp = nullptr;
            if (j == 1 && (i % 2 == 0) && i < 14) accp = acc_base + (size_t)i * CH;
            if (j == 0 && (i % 2 == 1))           accp = acc_base + (size_t)i * CH;
            if (i % 2 == 0) {
                lap_kernel<<<LAP_BLOCKS, 256, 0, stream>>>(row_ptr, col_s, val_s, ah, ph, N);
                gemm_mfma_kernel<8><<<gemm_grid, 256, 0, stream>>>(ah, al, ph, Wt_s, b,
                                                                   resp, outp, oh, ol,
                                                                   mask, accp,
                                                                   nullptr, denom, nullptr,
                                                                   N);
            } else {
                // avg step: bias2 computed inside the gemm from acc slot (i-1+j)
                const float* accv = acc_base + (size_t)(i - 1 + j) * CH;
                const float* Wb = blocks_W + (size_t)s * 256 * CH + 128 * CH;
                gemm_mfma_kernel<4><<<gemm_grid, 256, 0, stream>>>(ah, al, nullptr, Wt_s, b,
                                                                   resp, outp, oh, ol,
                                                                   mask, accp,
                                                                   accv, denom, Wb,
                                                                   N);
            }
        }
        float* t = xin; xin = xout; xout = t;
    }
    // after each layer the elu planes of the layer output land back in slot 0
    final_kernel<<<LAP_BLOCKS, 256, 0, stream>>>(hbh0, hbl0, conv2_W, conv2_b, inputs, out, N);
}